// Round 4
// baseline (854.955 us; speedup 1.0000x reference)
//
#include <hip/hip_runtime.h>
#include <hip/hip_bf16.h>

#define NB 64
#define ND 64
#define NQ 2048
#define NS 2048
#define QBLK 256
#define SBLK 64
#define QPB 8              // q-blocks per batch
#define NSPLIT 4           // s-range splits per (b,qb)
#define NSS (NS / NSPLIT)  // 512 s-cols per block
#define NT (NSS / SBLK)    // 8 tiles per block

typedef float f32x4 __attribute__((ext_vector_type(4)));
typedef short bf16x8 __attribute__((ext_vector_type(8)));
typedef int i32x4 __attribute__((ext_vector_type(4)));

// f32 -> bf16 via compiler-visible packed convert (m240: beats inline asm).
__device__ inline i32x4 pack8(const float* f) {
  union { __hip_bfloat162 h2[4]; i32x4 v; } u;
  #pragma unroll
  for (int p = 0; p < 4; ++p)
    u.h2[p] = __float22bfloat162_rn(float2{f[2 * p], f[2 * p + 1]});
  return u.v;
}

// bid = ss*512 + qb*64 + b  (b in low bits -> all blocks of batch b on XCD b%8)
// Block: batch b, 256 q-rows, s-cols [ss*512, +512). 4 waves x 64 q-rows.
// A (Q^T) in registers for the whole s-loop. S staged per 64-col tile in LDS
// bf16 [s][d] with 16B-slot XOR swizzle; double-buffered, register prefetch,
// ONE barrier per tile. grid=2048 -> 8 blocks/CU (100% wave residency).
__global__ __launch_bounds__(256, 8) void bmd_main(
    const float* __restrict__ Q, const float* __restrict__ S,
    float* __restrict__ part) {
  const int bid = blockIdx.x;
  const int b  = bid & (NB - 1);
  const int qb = (bid >> 6) & (QPB - 1);
  const int ss = bid >> 9;
  const int q0 = qb * QBLK;
  const int sbase = ss * NSS;
  const int tid = threadIdx.x;
  const int lane = tid & 63;
  const int w = tid >> 6;

  __shared__ char sT[2][SBLK * 128];

  const float* Qb = Q + (size_t)b * ND * NQ;
  const float* Sb = S + (size_t)b * ND * NS;

  // ---- A fragments: row = lane&15 (q), k = (lane>>4)*8+e (d) ----
  i32x4 afrag[4][2];  // [mf: 16 q-rows each][ks: k-step of 32]
  {
    const int qrow = q0 + w * 64 + (lane & 15);
    const int dbase = (lane >> 4) * 8;
    for (int mf = 0; mf < 4; ++mf)
      for (int ks = 0; ks < 2; ++ks) {
        const int d0 = ks * 32 + dbase;
        float f[8];
        #pragma unroll
        for (int e = 0; e < 8; ++e)
          f[e] = Qb[(size_t)(d0 + e) * NQ + (qrow + mf * 16)];
        afrag[mf][ks] = pack8(f);
      }
  }

  f32x4 rmax[4];
  #pragma unroll
  for (int mf = 0; mf < 4; ++mf)
    rmax[mf] = f32x4{-INFINITY, -INFINITY, -INFINITY, -INFINITY};

  // staging assignment: thread -> (d-block dbq, s-cols sl, sl+32)
  const int dbq = (tid >> 3) & 7;
  const int sl0 = (tid & 7) + (w << 3);
  const float* stage_src = Sb + (size_t)dbq * 8 * NS + sbase;
  int sl[2], byt[2];
  #pragma unroll
  for (int i = 0; i < 2; ++i) {
    sl[i] = sl0 + i * 32;
    byt[i] = sl[i] * 128 + ((dbq ^ (sl[i] & 7)) << 4);
  }

  // ---- stage tile 0 ----
  #pragma unroll
  for (int i = 0; i < 2; ++i) {
    const float* src = stage_src + sl[i];
    float f[8];
    #pragma unroll
    for (int e = 0; e < 8; ++e) f[e] = src[(size_t)e * NS];
    *reinterpret_cast<i32x4*>(sT[0] + byt[i]) = pack8(f);
  }
  __syncthreads();

  int cur = 0;
  for (int t = 0; t < NT; ++t) {
    // issue next tile's global loads (raw f32) -- latency hides under MFMAs
    float pf[2][8];
    const bool has_next = (t + 1 < NT);
    if (has_next) {
      const float* src = stage_src + (t + 1) * SBLK;
      #pragma unroll
      for (int i = 0; i < 2; ++i)
        #pragma unroll
        for (int e = 0; e < 8; ++e)
          pf[i][e] = src[sl[i] + (size_t)e * NS];
    }

    // ---- compute tile t from sT[cur]: nf in pairs for v_max3 fusion ----
    #pragma unroll
    for (int nfp = 0; nfp < 2; ++nfp) {
      const int scol0 = nfp * 32 + (lane & 15);
      bf16x8 bfr0[2], bfr1[2];
      #pragma unroll
      for (int ks = 0; ks < 2; ++ks) {
        const int slot = ((ks * 4 + (lane >> 4)) ^ (scol0 & 7)) << 4;
        bfr0[ks] = *reinterpret_cast<const bf16x8*>(sT[cur] + scol0 * 128 + slot);
        bfr1[ks] = *reinterpret_cast<const bf16x8*>(sT[cur] + (scol0 + 16) * 128 + slot);
      }
      #pragma unroll
      for (int mf = 0; mf < 4; ++mf) {
        const bf16x8 a0 = __builtin_bit_cast(bf16x8, afrag[mf][0]);
        const bf16x8 a1 = __builtin_bit_cast(bf16x8, afrag[mf][1]);
        f32x4 acc0 = {0.f, 0.f, 0.f, 0.f};
        f32x4 acc1 = {0.f, 0.f, 0.f, 0.f};
        acc0 = __builtin_amdgcn_mfma_f32_16x16x32_bf16(a0, bfr0[0], acc0, 0, 0, 0);
        acc1 = __builtin_amdgcn_mfma_f32_16x16x32_bf16(a0, bfr1[0], acc1, 0, 0, 0);
        acc0 = __builtin_amdgcn_mfma_f32_16x16x32_bf16(a1, bfr0[1], acc0, 0, 0, 0);
        acc1 = __builtin_amdgcn_mfma_f32_16x16x32_bf16(a1, bfr1[1], acc1, 0, 0, 0);
        #pragma unroll
        for (int j = 0; j < 4; ++j)
          rmax[mf][j] = fmaxf(rmax[mf][j], fmaxf(acc0[j], acc1[j]));  // v_max3
      }
    }

    // ---- convert + write tile t+1 into the other buffer ----
    if (has_next) {
      #pragma unroll
      for (int i = 0; i < 2; ++i)
        *reinterpret_cast<i32x4*>(sT[cur ^ 1] + byt[i]) = pack8(pf[i]);
    }
    __syncthreads();
    cur ^= 1;
  }

  // ---- epilogue: max across the 16 col-lanes -> per-row max to ws ----
  float* rowp = part + (size_t)bid * QBLK + w * 64;
  #pragma unroll
  for (int mf = 0; mf < 4; ++mf) {
    #pragma unroll
    for (int j = 0; j < 4; ++j) {
      float v = rmax[mf][j];
      v = fmaxf(v, __shfl_xor(v, 1));
      v = fmaxf(v, __shfl_xor(v, 2));
      v = fmaxf(v, __shfl_xor(v, 4));
      v = fmaxf(v, __shfl_xor(v, 8));
      if ((lane & 15) == 0)
        rowp[mf * 16 + (lane >> 4) * 4 + j] = v;  // row-max for this q-row
    }
  }
}

// out[b] = mean_q max_ss rowmax -- 64 blocks x 256 threads
__global__ void bmd_reduce(const float* __restrict__ part, float* __restrict__ out) {
  const int b = blockIdx.x;
  const int tid = threadIdx.x;
  __shared__ float ws4[4];
  float sum = 0.f;
  for (int qb = 0; qb < QPB; ++qb) {
    float m = -INFINITY;
    #pragma unroll
    for (int ssi = 0; ssi < NSPLIT; ++ssi)
      m = fmaxf(m, part[((size_t)((ssi * QPB + qb) * NB + b)) * QBLK + tid]);
    sum += m;
  }
  #pragma unroll
  for (int o = 1; o < 64; o <<= 1) sum += __shfl_xor(sum, o);
  if ((tid & 63) == 0) ws4[tid >> 6] = sum;
  __syncthreads();
  if (tid == 0) out[b] = (ws4[0] + ws4[1] + ws4[2] + ws4[3]) * (1.0f / NQ);
}

extern "C" void kernel_launch(void* const* d_in, const int* in_sizes, int n_in,
                              void* d_out, int out_size, void* d_ws, size_t ws_size,
                              hipStream_t stream) {
  const float* Q = (const float*)d_in[0];
  const float* S = (const float*)d_in[1];
  float* out = (float*)d_out;
  float* part = (float*)d_ws;  // NB*QPB*NSPLIT*QBLK = 512K floats = 2 MB
  bmd_main<<<dim3(NB * QPB * NSPLIT), dim3(256), 0, stream>>>(Q, S, part);
  bmd_reduce<<<dim3(NB), dim3(256), 0, stream>>>(part, out);
}

// Round 5
// 51.133 us; speedup vs baseline: 16.7202x; 16.7202x over previous
//
#include <hip/hip_runtime.h>
#include <hip/hip_bf16.h>

#define NB 64
#define ND 64
#define NQ 2048
#define NS 2048
#define QBLK 256
#define SBLK 64
#define QPB 8              // q-blocks per batch
#define NSPLIT 4           // s-range splits per (b,qb)
#define NSS (NS / NSPLIT)  // 512 s-cols per block
#define NT (NSS / SBLK)    // 8 tiles per block

typedef float f32x4 __attribute__((ext_vector_type(4)));
typedef short bf16x8 __attribute__((ext_vector_type(8)));
typedef int i32x4 __attribute__((ext_vector_type(4)));

// f32 -> bf16 via compiler-visible packed convert (m240: beats inline asm).
__device__ inline i32x4 pack8(const float* f) {
  union { __hip_bfloat162 h2[4]; i32x4 v; } u;
  #pragma unroll
  for (int p = 0; p < 4; ++p)
    u.h2[p] = __float22bfloat162_rn(float2{f[2 * p], f[2 * p + 1]});
  return u.v;
}

// bid = ss*512 + qb*64 + b  (b in low bits -> all blocks of batch b on XCD b%8)
// Block: batch b, 256 q-rows, s-cols [ss*512, +512). 4 waves x 64 q-rows.
// A (Q^T) in registers for the whole s-loop. S staged per 64-col tile in LDS
// bf16 [s][d] with 16B-slot XOR swizzle; double-buffered, register prefetch,
// ONE barrier per tile. grid=2048 -> 8 blocks/CU; VGPR<=64 (actual ~56) is
// what permits 8 waves/SIMD -- do NOT force it via launch_bounds (R4: cap=8
// drove the allocator to 32 VGPR + 3 GB of scratch spill, 855 us).
__global__ __launch_bounds__(256, 4) void bmd_main(
    const float* __restrict__ Q, const float* __restrict__ S,
    float* __restrict__ part) {
  const int bid = blockIdx.x;
  const int b  = bid & (NB - 1);
  const int qb = (bid >> 6) & (QPB - 1);
  const int ss = bid >> 9;
  const int q0 = qb * QBLK;
  const int sbase = ss * NSS;
  const int tid = threadIdx.x;
  const int lane = tid & 63;
  const int w = tid >> 6;

  __shared__ char sT[2][SBLK * 128];

  const float* Qb = Q + (size_t)b * ND * NQ;
  const float* Sb = S + (size_t)b * ND * NS;

  // ---- A fragments: row = lane&15 (q), k = (lane>>4)*8+e (d) ----
  i32x4 afrag[4][2];  // [mf: 16 q-rows each][ks: k-step of 32]
  {
    const int qrow = q0 + w * 64 + (lane & 15);
    const int dbase = (lane >> 4) * 8;
    for (int mf = 0; mf < 4; ++mf)
      for (int ks = 0; ks < 2; ++ks) {
        const int d0 = ks * 32 + dbase;
        float f[8];
        #pragma unroll
        for (int e = 0; e < 8; ++e)
          f[e] = Qb[(size_t)(d0 + e) * NQ + (qrow + mf * 16)];
        afrag[mf][ks] = pack8(f);
      }
  }

  f32x4 rmax[4];
  #pragma unroll
  for (int mf = 0; mf < 4; ++mf)
    rmax[mf] = f32x4{-INFINITY, -INFINITY, -INFINITY, -INFINITY};

  // staging assignment: thread -> (d-block dbq, s-cols sl, sl+32)
  const int dbq = (tid >> 3) & 7;
  const int sl0 = (tid & 7) + (w << 3);
  const float* stage_src = Sb + (size_t)dbq * 8 * NS + sbase;
  int sl[2], byt[2];
  #pragma unroll
  for (int i = 0; i < 2; ++i) {
    sl[i] = sl0 + i * 32;
    byt[i] = sl[i] * 128 + ((dbq ^ (sl[i] & 7)) << 4);
  }

  // ---- stage tile 0 ----
  #pragma unroll
  for (int i = 0; i < 2; ++i) {
    const float* src = stage_src + sl[i];
    float f[8];
    #pragma unroll
    for (int e = 0; e < 8; ++e) f[e] = src[(size_t)e * NS];
    *reinterpret_cast<i32x4*>(sT[0] + byt[i]) = pack8(f);
  }
  __syncthreads();

  int cur = 0;
  for (int t = 0; t < NT; ++t) {
    // issue next tile's global loads (raw f32) -- latency hides under MFMAs
    float pf[2][8];
    const bool has_next = (t + 1 < NT);
    if (has_next) {
      const float* src = stage_src + (t + 1) * SBLK;
      #pragma unroll
      for (int i = 0; i < 2; ++i)
        #pragma unroll
        for (int e = 0; e < 8; ++e)
          pf[i][e] = src[sl[i] + (size_t)e * NS];
    }

    // ---- compute tile t from sT[cur]: nf in pairs for v_max3 fusion ----
    #pragma unroll
    for (int nfp = 0; nfp < 2; ++nfp) {
      const int scol0 = nfp * 32 + (lane & 15);
      bf16x8 bfr0[2], bfr1[2];
      #pragma unroll
      for (int ks = 0; ks < 2; ++ks) {
        const int slot = ((ks * 4 + (lane >> 4)) ^ (scol0 & 7)) << 4;
        bfr0[ks] = *reinterpret_cast<const bf16x8*>(sT[cur] + scol0 * 128 + slot);
        bfr1[ks] = *reinterpret_cast<const bf16x8*>(sT[cur] + (scol0 + 16) * 128 + slot);
      }
      #pragma unroll
      for (int mf = 0; mf < 4; ++mf) {
        const bf16x8 a0 = __builtin_bit_cast(bf16x8, afrag[mf][0]);
        const bf16x8 a1 = __builtin_bit_cast(bf16x8, afrag[mf][1]);
        f32x4 acc0 = {0.f, 0.f, 0.f, 0.f};
        f32x4 acc1 = {0.f, 0.f, 0.f, 0.f};
        acc0 = __builtin_amdgcn_mfma_f32_16x16x32_bf16(a0, bfr0[0], acc0, 0, 0, 0);
        acc1 = __builtin_amdgcn_mfma_f32_16x16x32_bf16(a0, bfr1[0], acc1, 0, 0, 0);
        acc0 = __builtin_amdgcn_mfma_f32_16x16x32_bf16(a1, bfr0[1], acc0, 0, 0, 0);
        acc1 = __builtin_amdgcn_mfma_f32_16x16x32_bf16(a1, bfr1[1], acc1, 0, 0, 0);
        #pragma unroll
        for (int j = 0; j < 4; ++j)
          rmax[mf][j] = fmaxf(rmax[mf][j], fmaxf(acc0[j], acc1[j]));  // v_max3
      }
    }

    // ---- convert + write tile t+1 into the other buffer ----
    if (has_next) {
      #pragma unroll
      for (int i = 0; i < 2; ++i)
        *reinterpret_cast<i32x4*>(sT[cur ^ 1] + byt[i]) = pack8(pf[i]);
    }
    __syncthreads();
    cur ^= 1;
  }

  // ---- epilogue: max across the 16 col-lanes -> per-row max to ws ----
  float* rowp = part + (size_t)bid * QBLK + w * 64;
  #pragma unroll
  for (int mf = 0; mf < 4; ++mf) {
    #pragma unroll
    for (int j = 0; j < 4; ++j) {
      float v = rmax[mf][j];
      v = fmaxf(v, __shfl_xor(v, 1));
      v = fmaxf(v, __shfl_xor(v, 2));
      v = fmaxf(v, __shfl_xor(v, 4));
      v = fmaxf(v, __shfl_xor(v, 8));
      if ((lane & 15) == 0)
        rowp[mf * 16 + (lane >> 4) * 4 + j] = v;  // row-max for this q-row
    }
  }
}

// out[b] = mean_q max_ss rowmax -- 64 blocks x 256 threads
__global__ void bmd_reduce(const float* __restrict__ part, float* __restrict__ out) {
  const int b = blockIdx.x;
  const int tid = threadIdx.x;
  __shared__ float ws4[4];
  float sum = 0.f;
  for (int qb = 0; qb < QPB; ++qb) {
    float m = -INFINITY;
    #pragma unroll
    for (int ssi = 0; ssi < NSPLIT; ++ssi)
      m = fmaxf(m, part[((size_t)((ssi * QPB + qb) * NB + b)) * QBLK + tid]);
    sum += m;
  }
  #pragma unroll
  for (int o = 1; o < 64; o <<= 1) sum += __shfl_xor(sum, o);
  if ((tid & 63) == 0) ws4[tid >> 6] = sum;
  __syncthreads();
  if (tid == 0) out[b] = (ws4[0] + ws4[1] + ws4[2] + ws4[3]) * (1.0f / NQ);
}

extern "C" void kernel_launch(void* const* d_in, const int* in_sizes, int n_in,
                              void* d_out, int out_size, void* d_ws, size_t ws_size,
                              hipStream_t stream) {
  const float* Q = (const float*)d_in[0];
  const float* S = (const float*)d_in[1];
  float* out = (float*)d_out;
  float* part = (float*)d_ws;  // NB*QPB*NSPLIT*QBLK = 512K floats = 2 MB
  bmd_main<<<dim3(NB * QPB * NSPLIT), dim3(256), 0, stream>>>(Q, S, part);
  bmd_reduce<<<dim3(NB), dim3(256), 0, stream>>>(part, out);
}

// Round 6
// 49.047 us; speedup vs baseline: 17.4314x; 1.0425x over previous
//
#include <hip/hip_runtime.h>
#include <hip/hip_bf16.h>

#define NB 64
#define ND 64
#define NQ 2048
#define NS 2048
#define QBLK 512           // q-rows per block (8 waves x 64)
#define SBLK 64
#define QPB 4              // q-blocks per batch = NQ/QBLK
#define NSPLIT 4           // s-range splits per (b,qb)
#define NSS (NS / NSPLIT)  // 512 s-cols per block
#define NT (NSS / SBLK)    // 8 tiles per block

typedef float f32x4 __attribute__((ext_vector_type(4)));
typedef short bf16x8 __attribute__((ext_vector_type(8)));
typedef int i32x4 __attribute__((ext_vector_type(4)));

// f32 -> bf16 via compiler-visible packed convert (m240: beats inline asm).
__device__ inline i32x4 pack8(const float* f) {
  union { __hip_bfloat162 h2[4]; i32x4 v; } u;
  #pragma unroll
  for (int p = 0; p < 4; ++p)
    u.h2[p] = __float22bfloat162_rn(float2{f[2 * p], f[2 * p + 1]});
  return u.v;
}

// bid = ss*256 + qb*64 + b  (b in low bits -> all blocks of batch b on XCD b%8)
// Block: batch b, 512 q-rows (8 waves x 64), s-cols [ss*512, +512).
// A (Q^T) in registers for the whole s-loop. S staged per 64-col tile in LDS
// bf16 [s][d] with 16B-slot XOR swizzle; double-buffered, register prefetch
// (8 floats/thread), ONE barrier per tile. QBLK=512 halves staging redundancy
// vs 256 (each S element staged 4x total instead of 8x).
// R4 lesson: never cap VGPR below need -- (512,4) caps at 128, room to breathe.
__global__ __launch_bounds__(512, 4) void bmd_main(
    const float* __restrict__ Q, const float* __restrict__ S,
    float* __restrict__ part) {
  const int bid = blockIdx.x;
  const int b  = bid & (NB - 1);
  const int qb = (bid >> 6) & (QPB - 1);
  const int ss = bid >> 8;
  const int q0 = qb * QBLK;
  const int sbase = ss * NSS;
  const int tid = threadIdx.x;
  const int lane = tid & 63;
  const int w = tid >> 6;   // 0..7

  __shared__ char sT[2][SBLK * 128];

  const float* Qb = Q + (size_t)b * ND * NQ;
  const float* Sb = S + (size_t)b * ND * NS;

  // ---- A fragments: row = lane&15 (q), k = (lane>>4)*8+e (d) ----
  i32x4 afrag[4][2];  // [mf: 16 q-rows each][ks: k-step of 32]
  {
    const int qrow = q0 + w * 64 + (lane & 15);
    const int dbase = (lane >> 4) * 8;
    for (int mf = 0; mf < 4; ++mf)
      for (int ks = 0; ks < 2; ++ks) {
        const int d0 = ks * 32 + dbase;
        float f[8];
        #pragma unroll
        for (int e = 0; e < 8; ++e)
          f[e] = Qb[(size_t)(d0 + e) * NQ + (qrow + mf * 16)];
        afrag[mf][ks] = pack8(f);
      }
  }

  const f32x4 kZero = {0.f, 0.f, 0.f, 0.f};
  f32x4 rmax[4];
  #pragma unroll
  for (int mf = 0; mf < 4; ++mf)
    rmax[mf] = f32x4{-INFINITY, -INFINITY, -INFINITY, -INFINITY};

  // staging: thread -> (d-octet dbq, s-col sl); 512 threads cover 64s x 8 octets
  const int dbq = (tid >> 3) & 7;
  const int sl = (tid & 7) + ((tid >> 6) << 3);   // 0..63
  const int byt = sl * 128 + ((dbq ^ (sl & 7)) << 4);
  const float* stage_src = Sb + (size_t)dbq * 8 * NS + sbase;

  // ---- stage tile 0 ----
  {
    const float* src = stage_src + sl;
    float f[8];
    #pragma unroll
    for (int e = 0; e < 8; ++e) f[e] = src[(size_t)e * NS];
    *reinterpret_cast<i32x4*>(sT[0] + byt) = pack8(f);
  }
  __syncthreads();

  int cur = 0;
  for (int t = 0; t < NT; ++t) {
    // issue next tile's global loads (raw f32) -- hide under MFMAs
    float pf[8];
    const bool has_next = (t + 1 < NT);
    if (has_next) {
      const float* src = stage_src + (t + 1) * SBLK + sl;
      #pragma unroll
      for (int e = 0; e < 8; ++e) pf[e] = src[(size_t)e * NS];
    }

    // ---- compute tile t from sT[cur]: nf in pairs for v_max3 fusion ----
    #pragma unroll
    for (int nfp = 0; nfp < 2; ++nfp) {
      const int scol0 = nfp * 32 + (lane & 15);
      bf16x8 bfr0[2], bfr1[2];
      #pragma unroll
      for (int ks = 0; ks < 2; ++ks) {
        const int slot = ((ks * 4 + (lane >> 4)) ^ (scol0 & 7)) << 4;
        bfr0[ks] = *reinterpret_cast<const bf16x8*>(sT[cur] + scol0 * 128 + slot);
        bfr1[ks] = *reinterpret_cast<const bf16x8*>(sT[cur] + (scol0 + 16) * 128 + slot);
      }
      #pragma unroll
      for (int mf = 0; mf < 4; ++mf) {
        const bf16x8 a0 = __builtin_bit_cast(bf16x8, afrag[mf][0]);
        const bf16x8 a1 = __builtin_bit_cast(bf16x8, afrag[mf][1]);
        f32x4 acc0 = __builtin_amdgcn_mfma_f32_16x16x32_bf16(a0, bfr0[0], kZero, 0, 0, 0);
        f32x4 acc1 = __builtin_amdgcn_mfma_f32_16x16x32_bf16(a0, bfr1[0], kZero, 0, 0, 0);
        acc0 = __builtin_amdgcn_mfma_f32_16x16x32_bf16(a1, bfr0[1], acc0, 0, 0, 0);
        acc1 = __builtin_amdgcn_mfma_f32_16x16x32_bf16(a1, bfr1[1], acc1, 0, 0, 0);
        #pragma unroll
        for (int j = 0; j < 4; ++j)
          rmax[mf][j] = fmaxf(rmax[mf][j], fmaxf(acc0[j], acc1[j]));  // v_max3
      }
    }

    // ---- convert + write tile t+1 into the other buffer ----
    if (has_next)
      *reinterpret_cast<i32x4*>(sT[cur ^ 1] + byt) = pack8(pf);
    __syncthreads();
    cur ^= 1;
  }

  // ---- epilogue: max across the 16 col-lanes -> per-row max to ws ----
  float* rowp = part + (size_t)bid * QBLK + w * 64;
  #pragma unroll
  for (int mf = 0; mf < 4; ++mf) {
    #pragma unroll
    for (int j = 0; j < 4; ++j) {
      float v = rmax[mf][j];
      v = fmaxf(v, __shfl_xor(v, 1));
      v = fmaxf(v, __shfl_xor(v, 2));
      v = fmaxf(v, __shfl_xor(v, 4));
      v = fmaxf(v, __shfl_xor(v, 8));
      if ((lane & 15) == 0)
        rowp[mf * 16 + (lane >> 4) * 4 + j] = v;  // row-max for this q-row
    }
  }
}

// out[b] = mean_q max_ss rowmax -- 64 blocks x 256 threads, 8 q per thread
__global__ void bmd_reduce(const float* __restrict__ part, float* __restrict__ out) {
  const int b = blockIdx.x;
  const int tid = threadIdx.x;
  __shared__ float ws4[4];
  float sum = 0.f;
  #pragma unroll
  for (int k = 0; k < NQ / 256; ++k) {
    const int q = k * 256 + tid;
    const int qb = q >> 9;          // q / QBLK
    const int row = q & (QBLK - 1);
    float m = -INFINITY;
    #pragma unroll
    for (int ssi = 0; ssi < NSPLIT; ++ssi)
      m = fmaxf(m, part[((size_t)((ssi * QPB + qb) * NB + b)) * QBLK + row]);
    sum += m;
  }
  #pragma unroll
  for (int o = 1; o < 64; o <<= 1) sum += __shfl_xor(sum, o);
  if ((tid & 63) == 0) ws4[tid >> 6] = sum;
  __syncthreads();
  if (tid == 0) out[b] = (ws4[0] + ws4[1] + ws4[2] + ws4[3]) * (1.0f / NQ);
}

extern "C" void kernel_launch(void* const* d_in, const int* in_sizes, int n_in,
                              void* d_out, int out_size, void* d_ws, size_t ws_size,
                              hipStream_t stream) {
  const float* Q = (const float*)d_in[0];
  const float* S = (const float*)d_in[1];
  float* out = (float*)d_out;
  float* part = (float*)d_ws;  // NB*QPB*NSPLIT*QBLK = 512K floats = 2 MB
  bmd_main<<<dim3(NB * QPB * NSPLIT), dim3(512), 0, stream>>>(Q, S, part);
  bmd_reduce<<<dim3(NB), dim3(256), 0, stream>>>(part, out);
}